// Round 1
// baseline (446.446 us; speedup 1.0000x reference)
//
#include <hip/hip_runtime.h>
#include <math.h>

#define EPS 1e-6f
constexpr int N_ = 4, L_ = 4096, H_ = 16, D_ = 64;
constexpr int NH = N_ * H_;            // 64
constexpr int HD = H_ * D_;            // 1024
constexpr long NSTRIDE = (long)L_ * HD; // 4194304

// Scratch as device globals (ws_size-independent). All accumulator regions are
// zeroed by k0 every call; every other element is written before read each
// call, so graph replay is deterministic.
__device__ float g_qsum[NH * D_];
__device__ float g_ksum[NH * D_];
__device__ float g_qnr[NH * D_];
__device__ float g_knc[NH * D_];
__device__ float g_nr[NH * L_];
__device__ float g_coefrow[NH * L_];
__device__ float g_cr[NH * L_];
__device__ int   g_smax[NH];
__device__ float g_ssum[NH];
__device__ float g_kv[NH * D_ * D_];

__device__ __forceinline__ float sigm(float x) {
    return 1.0f / (1.0f + __expf(-x));
}

// ---------------- k0: zero accumulators ----------------
__global__ void k0_zero() {
    int i = blockIdx.x * blockDim.x + threadIdx.x;
    int st = gridDim.x * blockDim.x;
    for (int j = i; j < NH * D_; j += st) {
        g_qsum[j] = 0.f; g_ksum[j] = 0.f; g_qnr[j] = 0.f; g_knc[j] = 0.f;
    }
    for (int j = i; j < NH; j += st) { g_smax[j] = 0; g_ssum[j] = 0.f; }
    for (int j = i; j < NH * D_ * D_; j += st) g_kv[j] = 0.f;
}

// ---------------- k1: q_sum / k_sum over sequence ----------------
// grid (L/128, NH, 2), block 256. z=0 -> q, z=1 -> k.
__global__ __launch_bounds__(256) void k1_sums(const float* __restrict__ q,
                                               const float* __restrict__ k) {
    int nh = blockIdx.y, n = nh >> 4, h = nh & 15;
    const float* src = blockIdx.z ? k : q;
    float* dst = blockIdx.z ? g_ksum : g_qsum;
    int t = threadIdx.x, d = t & 63, rs = t >> 6;
    long base = (long)n * NSTRIDE + (long)h * D_ + d;
    int l0 = blockIdx.x * 128;
    float local = 0.f;
    for (int r = rs; r < 128; r += 4)
        local += sigm(src[base + (long)(l0 + r) * HD]);
    __shared__ float lds[256];
    lds[t] = local;
    __syncthreads();
    if (t < 64)
        atomicAdd(&dst[nh * D_ + t], lds[t] + lds[t + 64] + lds[t + 128] + lds[t + 192]);
}

// ---------------- k2: normalizer_row/col + qnr/knc accumulation ----------------
// grid (L/128, NH, 2), block 256 (4 waves, wave handles one row at a time).
// z=0: rows of q -> nr (stored), qnr += sq*nr
// z=1: rows of k -> nc (not stored), knc += sk*nc
__global__ __launch_bounds__(256) void k2_norm(const float* __restrict__ q,
                                               const float* __restrict__ k) {
    int nh = blockIdx.y, n = nh >> 4, h = nh & 15;
    bool colside = blockIdx.z != 0;
    const float* src = colside ? k : q;
    const float* sums = colside ? g_qsum : g_ksum;
    float* acc = colside ? g_knc : g_qnr;
    int t = threadIdx.x, lane = t & 63, w = t >> 6;
    float basev = sums[nh * D_ + lane] + EPS;
    long base = (long)n * NSTRIDE + (long)h * D_ + lane;
    int l0 = blockIdx.x * 128;
    float local = 0.f;
    for (int r = w; r < 128; r += 4) {
        int l = l0 + r;
        float s = sigm(src[base + (long)l * HD]);
        float p = (s + EPS) * basev;
        for (int m = 32; m; m >>= 1) p += __shfl_xor(p, m, 64);
        float inv = 1.f / p;
        if (!colside && lane == 0) g_nr[nh * L_ + l] = inv;
        local += s * inv;
    }
    atomicAdd(&acc[nh * D_ + lane], local);
}

// ---------------- k3: row_refine -> coef_row ; col_refine raw + max ----------------
// grid (L/128, NH, 2), block 256.
__global__ __launch_bounds__(256) void k3_refine(const float* __restrict__ q,
                                                 const float* __restrict__ k) {
    int nh = blockIdx.y, n = nh >> 4, h = nh & 15;
    bool colside = blockIdx.z != 0;
    const float* src = colside ? k : q;
    const float* accv = colside ? g_qnr : g_knc;
    int t = threadIdx.x, lane = t & 63, w = t >> 6;
    float basev = accv[nh * D_ + lane] + EPS;
    long base = (long)n * NSTRIDE + (long)h * D_ + lane;
    int l0 = blockIdx.x * 128;
    float wmax = 0.f;
    for (int r = w; r < 128; r += 4) {
        int l = l0 + r;
        float s = sigm(src[base + (long)l * HD]);
        float p = (s + EPS) * basev;
        for (int m = 32; m; m >>= 1) p += __shfl_xor(p, m, 64);
        if (!colside) {
            if (lane == 0) {
                float rr = sigm(p * ((float)L_ / (float)L_));
                g_coefrow[nh * L_ + l] = g_nr[nh * L_ + l] * rr;
            }
        } else {
            if (lane == 0) g_cr[nh * L_ + l] = p;
            wmax = fmaxf(wmax, p);
        }
    }
    // col_refine values are strictly positive -> int compare preserves order
    if (colside && lane == 0) atomicMax(&g_smax[nh], __float_as_int(wmax));
}

// ---------------- k3b: exp + per-head sum ----------------
// grid (L/1024, NH), block 256.
__global__ __launch_bounds__(256) void k3b_softmax() {
    int nh = blockIdx.y;
    int t = threadIdx.x;
    float mx = __int_as_float(g_smax[nh]);
    int base = nh * L_ + blockIdx.x * 1024;
    float local = 0.f;
    for (int j = t; j < 1024; j += 256) {
        float e = __expf(g_cr[base + j] - mx);
        g_cr[base + j] = e;
        local += e;
    }
    __shared__ float lds[256];
    lds[t] = local;
    __syncthreads();
    for (int s = 128; s; s >>= 1) {
        if (t < s) lds[t] += lds[t + s];
        __syncthreads();
    }
    if (t == 0) atomicAdd(&g_ssum[nh], lds[0]);
}

// ---------------- k4: kv[d][e] = sum_s sig(k)[s,d]*cr[s]*v[s,e] ----------------
// grid (S/512, NH), block 256. 32-row LDS tiles, 16 outputs/thread, atomic epilogue.
__global__ __launch_bounds__(256) void k4_kv(const float* __restrict__ k,
                                             const float* __restrict__ v) {
    int nh = blockIdx.y, n = nh >> 4, h = nh & 15;
    int t = threadIdx.x, e = t & 63, dg = t >> 6;
    float scale = (float)L_ / g_ssum[nh];   // softmax * S folded in
    __shared__ float kc[32][64];
    __shared__ float vt[32][64];
    __shared__ float crl[32];
    float acc[16];
#pragma unroll
    for (int i = 0; i < 16; i++) acc[i] = 0.f;
    int s0 = blockIdx.x * 512;
    long nbase = (long)n * NSTRIDE + (long)h * D_;
    for (int tile = 0; tile < 16; ++tile) {
        int sbase = s0 + tile * 32;
        if (t < 32) crl[t] = g_cr[nh * L_ + sbase + t] * scale;
        __syncthreads();
#pragma unroll
        for (int j = 0; j < 8; j++) {
            int elem = t + j * 256;
            int row = elem >> 6, d = elem & 63;
            long gi = nbase + (long)(sbase + row) * HD + d;
            kc[row][d] = sigm(k[gi]) * crl[row];
            vt[row][d] = v[gi];
        }
        __syncthreads();
#pragma unroll
        for (int s = 0; s < 32; s++) {
            float vv = vt[s][e];
            const float4* kp = (const float4*)&kc[s][dg * 16];
#pragma unroll
            for (int c = 0; c < 4; c++) {
                float4 kq = kp[c];
                acc[c * 4 + 0] += kq.x * vv;
                acc[c * 4 + 1] += kq.y * vv;
                acc[c * 4 + 2] += kq.z * vv;
                acc[c * 4 + 3] += kq.w * vv;
            }
        }
        __syncthreads();
    }
#pragma unroll
    for (int i = 0; i < 16; i++)
        atomicAdd(&g_kv[nh * 4096 + (dg * 16 + i) * 64 + e], acc[i]);
}

// ---------------- k5: out[l][e] = (sum_d sig(q)[l,d]*kv[d,e]) * coef_row[l] ----------------
// grid (L/64, NH), block 256. 64x64 block matmul; q tile padded (+1) to break
// the stride-64 4-way bank conflict on qt[l][d] reads.
__global__ __launch_bounds__(256) void k5_out(const float* __restrict__ q,
                                              float* __restrict__ out) {
    int nh = blockIdx.y, n = nh >> 4, h = nh & 15;
    int t = threadIdx.x;
    __shared__ float kvt[64 * 64];
    __shared__ float qt[64][65];
#pragma unroll
    for (int j = 0; j < 16; j++) kvt[t + j * 256] = g_kv[nh * 4096 + t + j * 256];
    int l0 = blockIdx.x * 64;
    long nbase = (long)n * NSTRIDE + (long)h * D_;
#pragma unroll
    for (int j = 0; j < 16; j++) {
        int elem = t + j * 256;
        int row = elem >> 6, d = elem & 63;
        qt[row][d] = sigm(q[nbase + (long)(l0 + row) * HD + d]);
    }
    __syncthreads();
    int e4 = t & 15, lg = t >> 4;
    float acc[4][4];
#pragma unroll
    for (int r = 0; r < 4; r++)
#pragma unroll
        for (int c = 0; c < 4; c++) acc[r][c] = 0.f;
#pragma unroll 8
    for (int d = 0; d < 64; ++d) {
        float4 kvv = *(const float4*)&kvt[d * 64 + e4 * 4];
#pragma unroll
        for (int r = 0; r < 4; r++) {
            float qv = qt[lg * 4 + r][d];
            acc[r][0] += qv * kvv.x;
            acc[r][1] += qv * kvv.y;
            acc[r][2] += qv * kvv.z;
            acc[r][3] += qv * kvv.w;
        }
    }
#pragma unroll
    for (int r = 0; r < 4; r++) {
        int l = l0 + lg * 4 + r;
        float coef = g_coefrow[nh * L_ + l];
        float4 o;
        o.x = acc[r][0] * coef;
        o.y = acc[r][1] * coef;
        o.z = acc[r][2] * coef;
        o.w = acc[r][3] * coef;
        *(float4*)&out[nbase + (long)l * HD + e4 * 4] = o;
    }
}

extern "C" void kernel_launch(void* const* d_in, const int* in_sizes, int n_in,
                              void* d_out, int out_size, void* d_ws, size_t ws_size,
                              hipStream_t stream) {
    const float* q = (const float*)d_in[0];
    const float* k = (const float*)d_in[1];
    const float* v = (const float*)d_in[2];
    float* out = (float*)d_out;

    k0_zero<<<256, 256, 0, stream>>>();
    k1_sums<<<dim3(L_ / 128, NH, 2), 256, 0, stream>>>(q, k);
    k2_norm<<<dim3(L_ / 128, NH, 2), 256, 0, stream>>>(q, k);
    k3_refine<<<dim3(L_ / 128, NH, 2), 256, 0, stream>>>(q, k);
    k3b_softmax<<<dim3(L_ / 1024, NH), 256, 0, stream>>>();
    k4_kv<<<dim3(L_ / 512, NH), 256, 0, stream>>>(k, v);
    k5_out<<<dim3(L_ / 64, NH), 256, 0, stream>>>(q, out);
}

// Round 2
// 376.345 us; speedup vs baseline: 1.1863x; 1.1863x over previous
//
#include <hip/hip_runtime.h>
#include <math.h>

#define EPS 1e-6f
constexpr int N_ = 4, L_ = 4096, H_ = 16, D_ = 64;
constexpr int NH = N_ * H_;             // 64
constexpr int HD = H_ * D_;             // 1024
constexpr long NSTRIDE = (long)L_ * HD; // 4194304

// Scratch as device globals. Accumulator regions zeroed by k0 every call;
// everything else is written before read each call (graph-replay safe).
__device__ float g_qsum[NH * D_];
__device__ float g_ksum[NH * D_];
__device__ float g_qnr[NH * D_];
__device__ float g_knc[NH * D_];
__device__ float g_nr[NH * L_];
__device__ float g_coefrow[NH * L_];
__device__ float g_cr[NH * L_];
__device__ int   g_smax[NH];
__device__ float g_ssum[NH];
__device__ float g_kv[NH * D_ * D_];

__device__ __forceinline__ float sigm(float x) {
    return 1.0f / (1.0f + __expf(-x));
}
__device__ __forceinline__ float4 sigm4(float4 x) {
    float4 r;
    r.x = sigm(x.x); r.y = sigm(x.y); r.z = sigm(x.z); r.w = sigm(x.w);
    return r;
}

// ---------------- k0: zero accumulators ----------------
__global__ void k0_zero() {
    int i = blockIdx.x * blockDim.x + threadIdx.x;
    int st = gridDim.x * blockDim.x;
    for (int j = i; j < NH * D_; j += st) {
        g_qsum[j] = 0.f; g_ksum[j] = 0.f; g_qnr[j] = 0.f; g_knc[j] = 0.f;
    }
    for (int j = i; j < NH; j += st) { g_smax[j] = 0; g_ssum[j] = 0.f; }
    for (int j = i; j < NH * D_ * D_; j += st) g_kv[j] = 0.f;
}

// ---------------- k1: q_sum / k_sum over sequence (vectorized) ----------------
// grid (L/128, NH, 2), block 256. z=0 -> q, z=1 -> k.
__global__ __launch_bounds__(256) void k1_sums(const float* __restrict__ q,
                                               const float* __restrict__ k) {
    int nh = blockIdx.y, n = nh >> 4, h = nh & 15;
    const float* src = blockIdx.z ? k : q;
    float* dst = blockIdx.z ? g_ksum : g_qsum;
    int t = threadIdx.x, c4 = t & 15, rg = t >> 4;
    long nbase = (long)n * NSTRIDE + (long)h * D_ + c4 * 4;
    int l0 = blockIdx.x * 128;
    float4 a = make_float4(0.f, 0.f, 0.f, 0.f);
#pragma unroll
    for (int j = 0; j < 8; ++j) {
        int r = rg + j * 16;
        float4 x = *(const float4*)&src[nbase + (long)(l0 + r) * HD];
        float4 s = sigm4(x);
        a.x += s.x; a.y += s.y; a.z += s.z; a.w += s.w;
    }
    __shared__ float4 lds[256];
    lds[t] = a;
    __syncthreads();
    if (t < 16) {
        float4 s = make_float4(0.f, 0.f, 0.f, 0.f);
#pragma unroll
        for (int g = 0; g < 16; ++g) {
            float4 b = lds[t + g * 16];
            s.x += b.x; s.y += b.y; s.z += b.z; s.w += b.w;
        }
        atomicAdd(&dst[nh * 64 + t * 4 + 0], s.x);
        atomicAdd(&dst[nh * 64 + t * 4 + 1], s.y);
        atomicAdd(&dst[nh * 64 + t * 4 + 2], s.z);
        atomicAdd(&dst[nh * 64 + t * 4 + 3], s.w);
    }
}

// ---------------- k2: normalizer_row/col + qnr/knc (LDS tile, no shuffles) ----------------
// grid (L/128, NH, 2), block 256.
// z=0: rows of q -> nr stored; qnr += sq*nr   z=1: rows of k -> nc; knc += sk*nc
__global__ __launch_bounds__(256) void k2_norm(const float* __restrict__ q,
                                               const float* __restrict__ k) {
    int nh = blockIdx.y, n = nh >> 4, h = nh & 15;
    bool colside = blockIdx.z != 0;
    const float* src = colside ? k : q;
    const float* sums = colside ? g_qsum : g_ksum;
    float* acc = colside ? g_knc : g_qnr;
    __shared__ float tile[128 * 64];
    __shared__ float bvec[64];
    __shared__ float nrl[128];
    __shared__ float part[256];
    int t = threadIdx.x;
    int l0 = blockIdx.x * 128;
    long nbase = (long)n * NSTRIDE + (long)h * D_;
    if (t < 64) bvec[t] = sums[nh * 64 + t] + EPS;
    // phase 1: coalesced load + sigmoid into stride-64 tile
#pragma unroll
    for (int j = 0; j < 8; ++j) {
        int e_ = t + j * 256;
        int r = e_ >> 4, c4 = e_ & 15;
        float4 x = *(const float4*)&src[nbase + (long)(l0 + r) * HD + c4 * 4];
        *(float4*)&tile[r * 64 + c4 * 4] = sigm4(x);
    }
    __syncthreads();
    // phase 2: row dots, rotated column index (bank-conflict-free)
    {
        int r = t & 127, h2 = t >> 7;
        float a = 0.f;
#pragma unroll
        for (int jj = 0; jj < 32; ++jj) {
            int j = (r + h2 * 32 + jj) & 63;
            a += (tile[r * 64 + j] + EPS) * bvec[j];
        }
        part[t] = a;
    }
    __syncthreads();
    if (t < 128) {
        float inv = 1.f / (part[t] + part[t + 128]);
        nrl[t] = inv;
        if (!colside) g_nr[nh * L_ + l0 + t] = inv;
    }
    __syncthreads();
    // phase 3: column accumulation acc[d] += sum_r tile[r][d]*nrl[r]
    {
        int d = t & 63, rg = t >> 6;
        float a = 0.f;
#pragma unroll
        for (int rr = 0; rr < 32; ++rr) {
            int r = rg * 32 + rr;
            a += tile[r * 64 + d] * nrl[r];
        }
        part[t] = a;
    }
    __syncthreads();
    if (t < 64)
        atomicAdd(&acc[nh * 64 + t], part[t] + part[t + 64] + part[t + 128] + part[t + 192]);
}

// ---------------- k3: row_refine -> coef_row ; col_refine raw + max ----------------
// grid (L/128, NH, 2), block 256. Same tile structure, no phase 3.
__global__ __launch_bounds__(256) void k3_refine(const float* __restrict__ q,
                                                 const float* __restrict__ k) {
    int nh = blockIdx.y, n = nh >> 4, h = nh & 15;
    bool colside = blockIdx.z != 0;
    const float* src = colside ? k : q;
    const float* accv = colside ? g_qnr : g_knc;
    __shared__ float tile[128 * 64];
    __shared__ float bvec[64];
    __shared__ float part[256];
    __shared__ float pmax[128];
    int t = threadIdx.x;
    int l0 = blockIdx.x * 128;
    long nbase = (long)n * NSTRIDE + (long)h * D_;
    if (t < 64) bvec[t] = accv[nh * 64 + t] + EPS;
#pragma unroll
    for (int j = 0; j < 8; ++j) {
        int e_ = t + j * 256;
        int r = e_ >> 4, c4 = e_ & 15;
        float4 x = *(const float4*)&src[nbase + (long)(l0 + r) * HD + c4 * 4];
        *(float4*)&tile[r * 64 + c4 * 4] = sigm4(x);
    }
    __syncthreads();
    {
        int r = t & 127, h2 = t >> 7;
        float a = 0.f;
#pragma unroll
        for (int jj = 0; jj < 32; ++jj) {
            int j = (r + h2 * 32 + jj) & 63;
            a += (tile[r * 64 + j] + EPS) * bvec[j];
        }
        part[t] = a;
    }
    __syncthreads();
    if (t < 128) {
        float p = part[t] + part[t + 128];
        int l = l0 + t;
        if (!colside) {
            // L/S == 1
            g_coefrow[nh * L_ + l] = g_nr[nh * L_ + l] * sigm(p);
        } else {
            g_cr[nh * L_ + l] = p;
            pmax[t] = p;
        }
    }
    __syncthreads();
    if (colside) {
        // block max over 128 values (values strictly positive -> int-compare ok)
        if (t < 64) pmax[t] = fmaxf(pmax[t], pmax[t + 64]);
        __syncthreads();
        if (t < 32) pmax[t] = fmaxf(pmax[t], pmax[t + 32]);
        __syncthreads();
        if (t == 0) {
            float m = pmax[0];
            for (int i = 1; i < 32; ++i) m = fmaxf(m, pmax[i]);
            atomicMax(&g_smax[nh], __float_as_int(m));
        }
    }
}

// ---------------- k3b: exp + per-head sum ----------------
// grid (L/1024, NH), block 256.
__global__ __launch_bounds__(256) void k3b_softmax() {
    int nh = blockIdx.y;
    int t = threadIdx.x;
    float mx = __int_as_float(g_smax[nh]);
    int base = nh * L_ + blockIdx.x * 1024;
    float local = 0.f;
    for (int j = t; j < 1024; j += 256) {
        float e = __expf(g_cr[base + j] - mx);
        g_cr[base + j] = e;
        local += e;
    }
    __shared__ float lds[256];
    lds[t] = local;
    __syncthreads();
    for (int s = 128; s; s >>= 1) {
        if (t < s) lds[t] += lds[t + s];
        __syncthreads();
    }
    if (t == 0) atomicAdd(&g_ssum[nh], lds[0]);
}

// ---------------- k4: kv[d][e] = sum_s sig(k)[s,d]*cr[s]*v[s,e] ----------------
// grid (S/256, NH), block 256. 4x4 register tile per thread, both operands b128.
__global__ __launch_bounds__(256) void k4_kv(const float* __restrict__ k,
                                             const float* __restrict__ v) {
    int nh = blockIdx.y, n = nh >> 4, h = nh & 15;
    int t = threadIdx.x;
    int e4 = t & 15, dg = t >> 4;  // e0 = 4*e4 (cols of v), d0 = 4*dg (cols of k)
    float scale = (float)L_ / g_ssum[nh];  // softmax * S folded in
    __shared__ float kc[32 * 64];
    __shared__ float vt[32 * 64];
    __shared__ float crl[32];
    float acc[4][4];
#pragma unroll
    for (int i = 0; i < 4; i++)
#pragma unroll
        for (int j = 0; j < 4; j++) acc[i][j] = 0.f;
    int s0 = blockIdx.x * 256;
    long nbase = (long)n * NSTRIDE + (long)h * D_;
    for (int tile = 0; tile < 8; ++tile) {
        int sb = s0 + tile * 32;
        __syncthreads();  // protect previous iteration's kc/vt reads
        if (t < 32) crl[t] = g_cr[nh * L_ + sb + t] * scale;
        __syncthreads();
#pragma unroll
        for (int j = 0; j < 2; ++j) {
            int e_ = t + j * 256;
            int r = e_ >> 4, c4 = e_ & 15;
            long gi = nbase + (long)(sb + r) * HD + c4 * 4;
            float4 kk = *(const float4*)&k[gi];
            float4 vv = *(const float4*)&v[gi];
            float c = crl[r];
            float4 ks = sigm4(kk);
            ks.x *= c; ks.y *= c; ks.z *= c; ks.w *= c;
            *(float4*)&kc[r * 64 + c4 * 4] = ks;
            *(float4*)&vt[r * 64 + c4 * 4] = vv;
        }
        __syncthreads();
#pragma unroll
        for (int s = 0; s < 32; ++s) {
            float4 kk = *(const float4*)&kc[s * 64 + dg * 4];
            float4 vv = *(const float4*)&vt[s * 64 + e4 * 4];
            acc[0][0] += kk.x * vv.x; acc[0][1] += kk.x * vv.y;
            acc[0][2] += kk.x * vv.z; acc[0][3] += kk.x * vv.w;
            acc[1][0] += kk.y * vv.x; acc[1][1] += kk.y * vv.y;
            acc[1][2] += kk.y * vv.z; acc[1][3] += kk.y * vv.w;
            acc[2][0] += kk.z * vv.x; acc[2][1] += kk.z * vv.y;
            acc[2][2] += kk.z * vv.z; acc[2][3] += kk.z * vv.w;
            acc[3][0] += kk.w * vv.x; acc[3][1] += kk.w * vv.y;
            acc[3][2] += kk.w * vv.z; acc[3][3] += kk.w * vv.w;
        }
    }
#pragma unroll
    for (int i = 0; i < 4; i++)
#pragma unroll
        for (int j = 0; j < 4; j++)
            atomicAdd(&g_kv[nh * 4096 + (dg * 4 + i) * 64 + e4 * 4 + j], acc[i][j]);
}

// ---------------- k5: out[l][e] = (sum_d sig(q)[l,d]*kv[d,e]) * coef_row[l] ----------------
// grid (L/64, NH), block 256. 64x64 block matmul; q tile padded (+1).
__global__ __launch_bounds__(256) void k5_out(const float* __restrict__ q,
                                              float* __restrict__ out) {
    int nh = blockIdx.y, n = nh >> 4, h = nh & 15;
    int t = threadIdx.x;
    __shared__ float kvt[64 * 64];
    __shared__ float qt[64][65];
#pragma unroll
    for (int j = 0; j < 4; j++)
        *(float4*)&kvt[(t + j * 256) * 4] = *(const float4*)&g_kv[nh * 4096 + (t + j * 256) * 4];
    int l0 = blockIdx.x * 64;
    long nbase = (long)n * NSTRIDE + (long)h * D_;
#pragma unroll
    for (int j = 0; j < 4; j++) {
        int e_ = t + j * 256;           // float4 index
        int r = e_ >> 4, c4 = e_ & 15;
        float4 x = *(const float4*)&q[nbase + (long)(l0 + r) * HD + c4 * 4];
        float4 s = sigm4(x);
        qt[r][c4 * 4 + 0] = s.x;
        qt[r][c4 * 4 + 1] = s.y;
        qt[r][c4 * 4 + 2] = s.z;
        qt[r][c4 * 4 + 3] = s.w;
    }
    __syncthreads();
    int e4 = t & 15, lg = t >> 4;
    float acc[4][4];
#pragma unroll
    for (int r = 0; r < 4; r++)
#pragma unroll
        for (int c = 0; c < 4; c++) acc[r][c] = 0.f;
#pragma unroll 8
    for (int d = 0; d < 64; ++d) {
        float4 kvv = *(const float4*)&kvt[d * 64 + e4 * 4];
#pragma unroll
        for (int r = 0; r < 4; r++) {
            float qv = qt[lg * 4 + r][d];
            acc[r][0] += qv * kvv.x;
            acc[r][1] += qv * kvv.y;
            acc[r][2] += qv * kvv.z;
            acc[r][3] += qv * kvv.w;
        }
    }
#pragma unroll
    for (int r = 0; r < 4; r++) {
        int l = l0 + lg * 4 + r;
        float coef = g_coefrow[nh * L_ + l];
        float4 o;
        o.x = acc[r][0] * coef;
        o.y = acc[r][1] * coef;
        o.z = acc[r][2] * coef;
        o.w = acc[r][3] * coef;
        *(float4*)&out[nbase + (long)l * HD + e4 * 4] = o;
    }
}

extern "C" void kernel_launch(void* const* d_in, const int* in_sizes, int n_in,
                              void* d_out, int out_size, void* d_ws, size_t ws_size,
                              hipStream_t stream) {
    const float* q = (const float*)d_in[0];
    const float* k = (const float*)d_in[1];
    const float* v = (const float*)d_in[2];
    float* out = (float*)d_out;

    k0_zero<<<256, 256, 0, stream>>>();
    k1_sums<<<dim3(L_ / 128, NH, 2), 256, 0, stream>>>(q, k);
    k2_norm<<<dim3(L_ / 128, NH, 2), 256, 0, stream>>>(q, k);
    k3_refine<<<dim3(L_ / 128, NH, 2), 256, 0, stream>>>(q, k);
    k3b_softmax<<<dim3(L_ / 1024, NH), 256, 0, stream>>>();
    k4_kv<<<dim3(L_ / 256, NH), 256, 0, stream>>>(k, v);
    k5_out<<<dim3(L_ / 64, NH), 256, 0, stream>>>(q, out);
}

// Round 4
// 333.453 us; speedup vs baseline: 1.3389x; 1.1286x over previous
//
#include <hip/hip_runtime.h>
#include <math.h>

#define EPS 1e-6f
constexpr int N_ = 4, L_ = 4096, H_ = 16, D_ = 64;
constexpr int NH = N_ * H_;             // 64
constexpr int HD = H_ * D_;             // 1024
constexpr long NSTRIDE = (long)L_ * HD; // 4194304
constexpr int KCHUNKS = 16;             // s-chunks for k4 (256 s each)

typedef __attribute__((ext_vector_type(8))) short short8;
typedef __attribute__((ext_vector_type(4))) float f32x4;

// Scratch as device globals. Accumulator regions zeroed by k0 every call;
// everything else is written before read each call (graph-replay safe).
__device__ float g_qsum[NH * D_];
__device__ float g_ksum[NH * D_];
__device__ float g_qnr[NH * D_];
__device__ float g_knc[NH * D_];
__device__ float g_nr[NH * L_];
__device__ float g_coefrow[NH * L_];
__device__ float g_cr[NH * L_];
__device__ int   g_smax[NH];
__device__ float g_ssum[NH];
__device__ float g_kv[NH * D_ * D_];
__device__ float g_kvpart[KCHUNKS * NH * D_ * D_];  // 16 MB

__device__ __forceinline__ float sigm(float x) {
    return 1.0f / (1.0f + __expf(-x));
}
__device__ __forceinline__ float4 sigm4(float4 x) {
    float4 r;
    r.x = sigm(x.x); r.y = sigm(x.y); r.z = sigm(x.z); r.w = sigm(x.w);
    return r;
}
// RNE round of fp32 bits to bf16, returned as high-16-aligned bits
__device__ __forceinline__ unsigned rne_hi(unsigned xb) {
    return (xb + 0x7fffu + ((xb >> 16) & 1u)) & 0xffff0000u;
}
// 3-component bf16 split: x ~= h1 + h2 + h3, residual <= 2^-27|x|.
// .x = (h1_bits<<16)|h2_bits packed, .y = h3_bits (low 16)
__device__ __forceinline__ uint2 pack_split3(float x) {
    unsigned xb = __float_as_uint(x);
    unsigned h1 = rne_hi(xb);
    float r1 = x - __uint_as_float(h1);
    unsigned h2 = rne_hi(__float_as_uint(r1));
    float r2 = r1 - __uint_as_float(h2);
    unsigned h3 = rne_hi(__float_as_uint(r2));
    uint2 o;
    o.x = h1 | (h2 >> 16);
    o.y = h3 >> 16;
    return o;
}

// ---------------- k0: zero accumulators ----------------
__global__ void k0_zero() {
    int i = blockIdx.x * blockDim.x + threadIdx.x;
    int st = gridDim.x * blockDim.x;
    for (int j = i; j < NH * D_; j += st) {
        g_qsum[j] = 0.f; g_ksum[j] = 0.f; g_qnr[j] = 0.f; g_knc[j] = 0.f;
    }
    for (int j = i; j < NH; j += st) { g_smax[j] = 0; g_ssum[j] = 0.f; }
}

// ---------------- k1: q_sum / k_sum over sequence (vectorized) ----------------
__global__ __launch_bounds__(256) void k1_sums(const float* __restrict__ q,
                                               const float* __restrict__ k) {
    int nh = blockIdx.y, n = nh >> 4, h = nh & 15;
    const float* src = blockIdx.z ? k : q;
    float* dst = blockIdx.z ? g_ksum : g_qsum;
    int t = threadIdx.x, c4 = t & 15, rg = t >> 4;
    long nbase = (long)n * NSTRIDE + (long)h * D_ + c4 * 4;
    int l0 = blockIdx.x * 128;
    float4 a = make_float4(0.f, 0.f, 0.f, 0.f);
#pragma unroll
    for (int j = 0; j < 8; ++j) {
        int r = rg + j * 16;
        float4 x = *(const float4*)&src[nbase + (long)(l0 + r) * HD];
        float4 s = sigm4(x);
        a.x += s.x; a.y += s.y; a.z += s.z; a.w += s.w;
    }
    __shared__ float4 lds[256];
    lds[t] = a;
    __syncthreads();
    if (t < 16) {
        float4 s = make_float4(0.f, 0.f, 0.f, 0.f);
#pragma unroll
        for (int g = 0; g < 16; ++g) {
            float4 b = lds[t + g * 16];
            s.x += b.x; s.y += b.y; s.z += b.z; s.w += b.w;
        }
        atomicAdd(&dst[nh * 64 + t * 4 + 0], s.x);
        atomicAdd(&dst[nh * 64 + t * 4 + 1], s.y);
        atomicAdd(&dst[nh * 64 + t * 4 + 2], s.z);
        atomicAdd(&dst[nh * 64 + t * 4 + 3], s.w);
    }
}

// ---------------- k2: normalizer_row/col + qnr/knc (LDS tile) ----------------
__global__ __launch_bounds__(256) void k2_norm(const float* __restrict__ q,
                                               const float* __restrict__ k) {
    int nh = blockIdx.y, n = nh >> 4, h = nh & 15;
    bool colside = blockIdx.z != 0;
    const float* src = colside ? k : q;
    const float* sums = colside ? g_qsum : g_ksum;
    float* acc = colside ? g_knc : g_qnr;
    __shared__ float tile[128 * 64];
    __shared__ float bvec[64];
    __shared__ float nrl[128];
    __shared__ float part[256];
    int t = threadIdx.x;
    int l0 = blockIdx.x * 128;
    long nbase = (long)n * NSTRIDE + (long)h * D_;
    if (t < 64) bvec[t] = sums[nh * 64 + t] + EPS;
#pragma unroll
    for (int j = 0; j < 8; ++j) {
        int e_ = t + j * 256;
        int r = e_ >> 4, c4 = e_ & 15;
        float4 x = *(const float4*)&src[nbase + (long)(l0 + r) * HD + c4 * 4];
        *(float4*)&tile[r * 64 + c4 * 4] = sigm4(x);
    }
    __syncthreads();
    {
        int r = t & 127, h2 = t >> 7;
        float a = 0.f;
#pragma unroll
        for (int jj = 0; jj < 32; ++jj) {
            int j = (r + h2 * 32 + jj) & 63;
            a += (tile[r * 64 + j] + EPS) * bvec[j];
        }
        part[t] = a;
    }
    __syncthreads();
    if (t < 128) {
        float inv = 1.f / (part[t] + part[t + 128]);
        nrl[t] = inv;
        if (!colside) g_nr[nh * L_ + l0 + t] = inv;
    }
    __syncthreads();
    {
        int d = t & 63, rg = t >> 6;
        float a = 0.f;
#pragma unroll
        for (int rr = 0; rr < 32; ++rr) {
            int r = rg * 32 + rr;
            a += tile[r * 64 + d] * nrl[r];
        }
        part[t] = a;
    }
    __syncthreads();
    if (t < 64)
        atomicAdd(&acc[nh * 64 + t], part[t] + part[t + 64] + part[t + 128] + part[t + 192]);
}

// ---------------- k3: row_refine -> coef_row ; col_refine raw + max ----------------
__global__ __launch_bounds__(256) void k3_refine(const float* __restrict__ q,
                                                 const float* __restrict__ k) {
    int nh = blockIdx.y, n = nh >> 4, h = nh & 15;
    bool colside = blockIdx.z != 0;
    const float* src = colside ? k : q;
    const float* accv = colside ? g_qnr : g_knc;
    __shared__ float tile[128 * 64];
    __shared__ float bvec[64];
    __shared__ float part[256];
    __shared__ float pmax[128];
    int t = threadIdx.x;
    int l0 = blockIdx.x * 128;
    long nbase = (long)n * NSTRIDE + (long)h * D_;
    if (t < 64) bvec[t] = accv[nh * 64 + t] + EPS;
#pragma unroll
    for (int j = 0; j < 8; ++j) {
        int e_ = t + j * 256;
        int r = e_ >> 4, c4 = e_ & 15;
        float4 x = *(const float4*)&src[nbase + (long)(l0 + r) * HD + c4 * 4];
        *(float4*)&tile[r * 64 + c4 * 4] = sigm4(x);
    }
    __syncthreads();
    {
        int r = t & 127, h2 = t >> 7;
        float a = 0.f;
#pragma unroll
        for (int jj = 0; jj < 32; ++jj) {
            int j = (r + h2 * 32 + jj) & 63;
            a += (tile[r * 64 + j] + EPS) * bvec[j];
        }
        part[t] = a;
    }
    __syncthreads();
    if (t < 128) {
        float p = part[t] + part[t + 128];
        int l = l0 + t;
        if (!colside) {
            g_coefrow[nh * L_ + l] = g_nr[nh * L_ + l] * sigm(p);
        } else {
            g_cr[nh * L_ + l] = p;
            pmax[t] = p;
        }
    }
    __syncthreads();
    if (colside) {
        if (t < 64) pmax[t] = fmaxf(pmax[t], pmax[t + 64]);
        __syncthreads();
        if (t < 32) pmax[t] = fmaxf(pmax[t], pmax[t + 32]);
        __syncthreads();
        if (t == 0) {
            float m = pmax[0];
            for (int i = 1; i < 32; ++i) m = fmaxf(m, pmax[i]);
            atomicMax(&g_smax[nh], __float_as_int(m));
        }
    }
}

// ---------------- k3b: exp + per-head sum ----------------
__global__ __launch_bounds__(256) void k3b_softmax() {
    int nh = blockIdx.y;
    int t = threadIdx.x;
    float mx = __int_as_float(g_smax[nh]);
    int base = nh * L_ + blockIdx.x * 1024;
    float local = 0.f;
    for (int j = t; j < 1024; j += 256) {
        float e = __expf(g_cr[base + j] - mx);
        g_cr[base + j] = e;
        local += e;
    }
    __shared__ float lds[256];
    lds[t] = local;
    __syncthreads();
    for (int s = 128; s; s >>= 1) {
        if (t < s) lds[t] += lds[t + s];
        __syncthreads();
    }
    if (t == 0) atomicAdd(&g_ssum[nh], lds[0]);
}

// ---------------- k4: kv partials via 3-way split-bf16 MFMA ----------------
// grid (KCHUNKS, NH), block 256 (4 waves). Each block: 256 s-rows in 8
// sub-tiles of 32. Wave w owns d-strip [16w,16w+16) x all 64 e.
// a = a1+a2+a3 (bf16 each, residual <= 2^-27|a|); 6 MFMAs per product group
// (a1b1,a1b2,a2b1,a1b3,a3b1,a2b2) -> fp32-grade, margin-safe precision.
__global__ __launch_bounds__(256) void k4_kv(const float* __restrict__ k,
                                             const float* __restrict__ v) {
    int nh = blockIdx.y, n = nh >> 4, h = nh & 15;
    int t = threadIdx.x, lane = t & 63, wv = t >> 6;
    __shared__ uint2 ktile[32 * 67];   // row=s (32), col=d; split sig(k)*cr
    __shared__ uint2 vtile[32 * 67];   // row=s (32), col=e; split v
    __shared__ float crs[256];
    float scale = (float)L_ / g_ssum[nh];
    int s0blk = blockIdx.x * 256;
    crs[t] = g_cr[nh * L_ + s0blk + t] * scale;

    f32x4 acc[4];
#pragma unroll
    for (int e = 0; e < 4; ++e) acc[e] = (f32x4){0.f, 0.f, 0.f, 0.f};

    long nbase = (long)n * NSTRIDE + (long)h * D_;
    int m = lane & 15, qd = lane >> 4;

    for (int sub = 0; sub < 8; ++sub) {
        int s0 = sub * 32;
        __syncthreads();   // covers crs (first iter) + prior tile reads
        // stage 32x64 of k and v, 3-way split
#pragma unroll
        for (int j = 0; j < 2; ++j) {
            int idx = t + j * 256;
            int r = idx >> 4, c4 = idx & 15;
            long gi = nbase + (long)(s0blk + s0 + r) * HD + c4 * 4;
            float4 kk = *(const float4*)&k[gi];
            float4 vv = *(const float4*)&v[gi];
            float c = crs[s0 + r];
            float4 ks4 = sigm4(kk);
            uint2 kp0 = pack_split3(ks4.x * c), kp1 = pack_split3(ks4.y * c);
            uint2 kp2 = pack_split3(ks4.z * c), kp3 = pack_split3(ks4.w * c);
            uint2 vp0 = pack_split3(vv.x), vp1 = pack_split3(vv.y);
            uint2 vp2 = pack_split3(vv.z), vp3 = pack_split3(vv.w);
            uint2* kdst = &ktile[r * 67 + c4 * 4];
            uint2* vdst = &vtile[r * 67 + c4 * 4];
            *(uint4*)&kdst[0] = make_uint4(kp0.x, kp0.y, kp1.x, kp1.y);
            *(uint4*)&kdst[2] = make_uint4(kp2.x, kp2.y, kp3.x, kp3.y);
            *(uint4*)&vdst[0] = make_uint4(vp0.x, vp0.y, vp1.x, vp1.y);
            *(uint4*)&vdst[2] = make_uint4(vp2.x, vp2.y, vp3.x, vp3.y);
        }
        __syncthreads();
        // one K=32 MFMA step over these 32 s-rows
        {
            // A frag: A[m=lane&15][k=qd*8+j] = K[s=qd*8+j][d=wv*16+m]
            short8 a1, a2, a3;
#pragma unroll
            for (int j = 0; j < 8; ++j) {
                uint2 aw = ktile[(qd * 8 + j) * 67 + wv * 16 + m];
                a1[j] = (short)(aw.x >> 16);
                a2[j] = (short)(aw.x & 0xffffu);
                a3[j] = (short)(aw.y);
            }
#pragma unroll
            for (int e = 0; e < 4; ++e) {
                short8 b1, b2, b3;
#pragma unroll
                for (int j = 0; j < 8; ++j) {
                    uint2 bw = vtile[(qd * 8 + j) * 67 + e * 16 + m];
                    b1[j] = (short)(bw.x >> 16);
                    b2[j] = (short)(bw.x & 0xffffu);
                    b3[j] = (short)(bw.y);
                }
                acc[e] = __builtin_amdgcn_mfma_f32_16x16x32_bf16(a1, b1, acc[e], 0, 0, 0);
                acc[e] = __builtin_amdgcn_mfma_f32_16x16x32_bf16(a1, b2, acc[e], 0, 0, 0);
                acc[e] = __builtin_amdgcn_mfma_f32_16x16x32_bf16(a2, b1, acc[e], 0, 0, 0);
                acc[e] = __builtin_amdgcn_mfma_f32_16x16x32_bf16(a1, b3, acc[e], 0, 0, 0);
                acc[e] = __builtin_amdgcn_mfma_f32_16x16x32_bf16(a3, b1, acc[e], 0, 0, 0);
                acc[e] = __builtin_amdgcn_mfma_f32_16x16x32_bf16(a2, b2, acc[e], 0, 0, 0);
            }
        }
    }
    // epilogue: C/D layout col=lane&15, row=qd*4+reg. wave wv owns d-strip.
    float* dst = &g_kvpart[((long)blockIdx.x * NH + nh) * 4096];
#pragma unroll
    for (int e = 0; e < 4; ++e) {
#pragma unroll
        for (int r = 0; r < 4; ++r) {
            int d = wv * 16 + qd * 4 + r;
            int ec = e * 16 + m;
            dst[d * 64 + ec] = acc[e][r];
        }
    }
}

// ---------------- k4b: reduce kv partials ----------------
__global__ __launch_bounds__(256) void k4b_reduce() {
    int nh = blockIdx.x, t = threadIdx.x;
#pragma unroll
    for (int j = 0; j < 4; ++j) {
        int i4 = t + j * 256;
        float4 s = make_float4(0.f, 0.f, 0.f, 0.f);
        for (int c = 0; c < KCHUNKS; ++c) {
            float4 p = ((const float4*)&g_kvpart[((long)c * NH + nh) * 4096])[i4];
            s.x += p.x; s.y += p.y; s.z += p.z; s.w += p.w;
        }
        ((float4*)&g_kv[nh * 4096])[i4] = s;
    }
}

// ---------------- k5: out = (sig(q) @ kv) * coef_row ----------------
__global__ __launch_bounds__(256) void k5_out(const float* __restrict__ q,
                                              float* __restrict__ out) {
    int nh = blockIdx.y, n = nh >> 4, h = nh & 15;
    int t = threadIdx.x;
    __shared__ float kvt[64 * 64];
    __shared__ float qt[64][65];
#pragma unroll
    for (int j = 0; j < 4; j++)
        *(float4*)&kvt[(t + j * 256) * 4] = *(const float4*)&g_kv[nh * 4096 + (t + j * 256) * 4];
    int l0 = blockIdx.x * 64;
    long nbase = (long)n * NSTRIDE + (long)h * D_;
#pragma unroll
    for (int j = 0; j < 4; j++) {
        int e_ = t + j * 256;
        int r = e_ >> 4, c4 = e_ & 15;
        float4 x = *(const float4*)&q[nbase + (long)(l0 + r) * HD + c4 * 4];
        float4 s = sigm4(x);
        qt[r][c4 * 4 + 0] = s.x;
        qt[r][c4 * 4 + 1] = s.y;
        qt[r][c4 * 4 + 2] = s.z;
        qt[r][c4 * 4 + 3] = s.w;
    }
    __syncthreads();
    int e4 = t & 15, lg = t >> 4;
    float acc[4][4];
#pragma unroll
    for (int r = 0; r < 4; r++)
#pragma unroll
        for (int c = 0; c < 4; c++) acc[r][c] = 0.f;
#pragma unroll 8
    for (int d = 0; d < 64; ++d) {
        float4 kvv = *(const float4*)&kvt[d * 64 + e4 * 4];
#pragma unroll
        for (int r = 0; r < 4; r++) {
            float qv = qt[lg * 4 + r][d];
            acc[r][0] += qv * kvv.x;
            acc[r][1] += qv * kvv.y;
            acc[r][2] += qv * kvv.z;
            acc[r][3] += qv * kvv.w;
        }
    }
#pragma unroll
    for (int r = 0; r < 4; r++) {
        int l = l0 + lg * 4 + r;
        float coef = g_coefrow[nh * L_ + l];
        float4 o;
        o.x = acc[r][0] * coef;
        o.y = acc[r][1] * coef;
        o.z = acc[r][2] * coef;
        o.w = acc[r][3] * coef;
        *(float4*)&out[nbase + (long)l * HD + e4 * 4] = o;
    }
}

extern "C" void kernel_launch(void* const* d_in, const int* in_sizes, int n_in,
                              void* d_out, int out_size, void* d_ws, size_t ws_size,
                              hipStream_t stream) {
    const float* q = (const float*)d_in[0];
    const float* k = (const float*)d_in[1];
    const float* v = (const float*)d_in[2];
    float* out = (float*)d_out;

    k0_zero<<<64, 256, 0, stream>>>();
    k1_sums<<<dim3(L_ / 128, NH, 2), 256, 0, stream>>>(q, k);
    k2_norm<<<dim3(L_ / 128, NH, 2), 256, 0, stream>>>(q, k);
    k3_refine<<<dim3(L_ / 128, NH, 2), 256, 0, stream>>>(q, k);
    k3b_softmax<<<dim3(L_ / 1024, NH), 256, 0, stream>>>();
    k4_kv<<<dim3(KCHUNKS, NH), 256, 0, stream>>>(k, v);
    k4b_reduce<<<NH, 256, 0, stream>>>();
    k5_out<<<dim3(L_ / 64, NH), 256, 0, stream>>>(q, out);
}